// Round 12
// baseline (259.518 us; speedup 1.0000x reference)
//
#include <hip/hip_runtime.h>
#include <hip/hip_bf16.h>
#include <math.h>

typedef __bf16 bf16_t;
typedef __bf16 bf16x8 __attribute__((ext_vector_type(8)));
typedef float floatx4 __attribute__((ext_vector_type(4)));

typedef __attribute__((address_space(1))) void gvoid_t;
typedef __attribute__((address_space(3))) void lvoid_t;

// Async 16B/lane global->LDS. Pass the WAVE-UNIFORM LDS base; HW writes lane l
// at base + l*16. Global address is per-lane. (inttoptr as3 = low-32 LDS offset.)
static __device__ __forceinline__ void gload_lds16(const bf16_t* g, const bf16_t* l) {
    __builtin_amdgcn_global_load_lds((gvoid_t*)(size_t)g,
                                     (lvoid_t*)(unsigned)(size_t)l,
                                     16, 0, 0);
}

// native RNE f32->bf16 pair pack (compiler emits v_cvt_pk_bf16_f32)
static __device__ __forceinline__ unsigned pack_bf2(float lo, float hi) {
    bf16_t a = (bf16_t)lo, b = (bf16_t)hi;
    return (unsigned)__builtin_bit_cast(unsigned short, a)
         | ((unsigned)__builtin_bit_cast(unsigned short, b) << 16);
}

static __device__ inline void store_c(float* C, size_t i, float v) { C[i] = v; }
static __device__ inline void store_c(bf16_t* C, size_t i, float v) { C[i] = (bf16_t)v; }

// convert 8 fp32 -> 8 bf16 (16B store)
static __device__ inline void cvt8(const float* src, bf16_t* dst, size_t idx) {
    float4 a = *(const float4*)(src + idx);
    float4 c = *(const float4*)(src + idx + 4);
    uint4 u;
    u.x = pack_bf2(a.x, a.y);
    u.y = pack_bf2(a.z, a.w);
    u.z = pack_bf2(c.x, c.y);
    u.w = pack_bf2(c.z, c.w);
    *(uint4*)(dst + idx) = u;
}

// ---------------------------------------------------------------------------
// m97-class GEMM body: C = (A[M,K]*B[N,K]^T (+bias_col)(+bias_row)) * cscale.
// TM=TN=128, BK=32, 4 waves (2x2), 4x4 16x16x32 fragments per wave.
// Staging via global_load_lds (linear LDS); bank conflicts broken by XOR-
// swizzling the 16B chunk index with ((row>>1)&3) on BOTH the global source
// address (write side is linear) and the ds_read address.
// Needs >=4 blocks/CU for barrier-drain hiding (r10/r11 lesson).
// ---------------------------------------------------------------------------
template <typename TC>
__device__ inline void gemm_body128(
    const bf16_t* __restrict__ A, int lda,
    const bf16_t* __restrict__ B, int ldb,
    const float* __restrict__ bias_col, const float* __restrict__ bias_row,
    float cscale,
    TC* __restrict__ C, int ldc, int K, int m0, int n0)
{
    __shared__ bf16_t As[128 * 32];
    __shared__ bf16_t Bs[128 * 32];

    const int tid = threadIdx.x;
    const int lane = tid & 63, wave = tid >> 6;
    const int wm = wave & 1, wn = wave >> 1;
    const int lo16 = lane & 15, quad = lane >> 4;

    // staging map: thread covers (row = i*64 + tid/4, 16B chunk slot = tid%4)
    const int r0 = tid >> 2;
    const int s0 = tid & 3;
    const int c0 = s0 ^ ((r0 >> 1) & 3);   // ((64+r0)>>1)&3 == (r0>>1)&3, same chunk both issues
    const bf16_t* ga0 = A + (size_t)(m0 + r0) * lda + c0 * 8;
    const bf16_t* ga1 = A + (size_t)(m0 + 64 + r0) * lda + c0 * 8;
    const bf16_t* gb0 = B + (size_t)(n0 + r0) * ldb + c0 * 8;
    const bf16_t* gb1 = B + (size_t)(n0 + 64 + r0) * ldb + c0 * 8;
    const bf16_t* la0 = As + wave * 512;           // wave-uniform LDS bases
    const bf16_t* la1 = As + 2048 + wave * 512;
    const bf16_t* lb0 = Bs + wave * 512;
    const bf16_t* lb1 = Bs + 2048 + wave * 512;

    // swizzled fragment read offsets (elems), precomputed
    int aoff[4], boff[4];
#pragma unroll
    for (int t = 0; t < 4; ++t) {
        const int ra = wm * 64 + t * 16 + lo16;
        aoff[t] = ra * 32 + ((quad ^ ((ra >> 1) & 3)) << 3);
        const int rb = wn * 64 + t * 16 + lo16;
        boff[t] = rb * 32 + ((quad ^ ((rb >> 1) & 3)) << 3);
    }

    floatx4 acc[4][4] = {};

    for (int k0 = 0; k0 < K; k0 += 32) {
        __syncthreads();                 // prev ds_reads done before overwrite
        gload_lds16(ga0 + k0, la0);
        gload_lds16(ga1 + k0, la1);
        gload_lds16(gb0 + k0, lb0);
        gload_lds16(gb1 + k0, lb1);
        __syncthreads();                 // compiler drains vmcnt(0) before barrier

        bf16x8 af[4], bfv[4];
#pragma unroll
        for (int t = 0; t < 4; ++t) {
            af[t]  = *(const bf16x8*)(As + aoff[t]);
            bfv[t] = *(const bf16x8*)(Bs + boff[t]);
        }
#pragma unroll
        for (int mt = 0; mt < 4; ++mt)
#pragma unroll
            for (int nt = 0; nt < 4; ++nt)
                acc[mt][nt] = __builtin_amdgcn_mfma_f32_16x16x32_bf16(
                    af[mt], bfv[nt], acc[mt][nt], 0, 0, 0);
    }

#pragma unroll
    for (int nt = 0; nt < 4; ++nt) {
        const int gn = n0 + wn * 64 + nt * 16 + lo16;
        const float bc = bias_col ? bias_col[gn] : 0.f;
#pragma unroll
        for (int mt = 0; mt < 4; ++mt) {
#pragma unroll
            for (int r = 0; r < 4; ++r) {
                const int gm = m0 + wm * 64 + mt * 16 + quad * 4 + r;
                float v = acc[mt][nt][r] + bc;
                if (bias_row) v += bias_row[gm];
                store_c(C, (size_t)gm * ldc + gn, v * cscale);
            }
        }
    }
}

// Bulk fp32->bf16 of q/k/v inputs and the 4 weight matrices. 8192 elems/block.
__global__ __launch_bounds__(256) void prep(
    const float* __restrict__ query, const float* __restrict__ key, const float* __restrict__ value,
    const float* __restrict__ Wq, const float* __restrict__ Wk,
    const float* __restrict__ Wv, const float* __restrict__ Wo,
    bf16_t* qB, bf16_t* kB, bf16_t* vB,
    bf16_t* wqB, bf16_t* wkB, bf16_t* wvB, bf16_t* woB)
{
    const int b = blockIdx.x;
    const float* src; bf16_t* dst; size_t base;
    if      (b < 256) { src = query; dst = qB;  base = (size_t)b * 8192; }
    else if (b < 512) { src = key;   dst = kB;  base = (size_t)(b - 256) * 8192; }
    else if (b < 768) { src = value; dst = vB;  base = (size_t)(b - 512) * 8192; }
    else if (b < 800) { src = Wq;    dst = wqB; base = (size_t)(b - 768) * 8192; }
    else if (b < 832) { src = Wk;    dst = wkB; base = (size_t)(b - 800) * 8192; }
    else if (b < 864) { src = Wv;    dst = wvB; base = (size_t)(b - 832) * 8192; }
    else              { src = Wo;    dst = woB; base = (size_t)(b - 864) * 8192; }
#pragma unroll
    for (int it = 0; it < 4; ++it)
        cvt8(src, dst, base + (size_t)it * 2048 + threadIdx.x * 8);
}

// QKV projections: 3 GEMMs x 128 blocks (128x128 tiles) + 2048 sg fp32->bf16
// convert blocks appended (converts fill idle CU residency; sgb isn't consumed
// until sgconv two kernels later).
// Q output is pre-scaled by (1/sqrt(D))*log2(e) so flash can use a bare exp2.
__global__ __launch_bounds__(256) void proj_qkv(
    const bf16_t* __restrict__ qB, const bf16_t* __restrict__ wqB, const float* __restrict__ bq,
    const bf16_t* __restrict__ kB, const bf16_t* __restrict__ wkB, const float* __restrict__ bk,
    const bf16_t* __restrict__ wvB, const bf16_t* __restrict__ vB, const float* __restrict__ bv,
    bf16_t* __restrict__ q, bf16_t* __restrict__ k, bf16_t* __restrict__ vt, float qscale,
    const float* __restrict__ sg, bf16_t* __restrict__ sgb)
{
    const int b = blockIdx.x;
    if (b >= 384) {   // 2048 convert blocks: 8192 elems each
        const size_t base = (size_t)(b - 384) * 8192;
#pragma unroll
        for (int it = 0; it < 4; ++it)
            cvt8(sg, sgb, base + (size_t)it * 2048 + threadIdx.x * 8);
        return;
    }
    const int i = b & 127;
    if (b < 256) {
        const int m0 = (i & 31) * 128, n0 = (i >> 5) * 128;  // M=4096, N=512
        if (b < 128)
            gemm_body128<bf16_t>(qB, 512, wqB, 512, bq, nullptr, qscale, q, 512, 512, m0, n0);
        else
            gemm_body128<bf16_t>(kB, 512, wkB, 512, bk, nullptr, 1.f, k, 512, 512, m0, n0);
    } else {
        const int m0 = (i & 3) * 128, n0 = (i >> 2) * 128;   // M=512, N=4096 (vt transposed)
        gemm_body128<bf16_t>(wvB, 512, vB, 512, nullptr, bv, 1.f, vt, 4096, 512, m0, n0);
    }
}

// ---------------------------------------------------------------------------
// sgconv: 128x128 tiles (874-TF-class body), 8-way K-split of 512 each ->
// grid 1024 = 4 blocks/CU (r11 lesson: 4/CU + cheap bf16 partials wins;
// r10 lesson: 64^2 tile caps at ~343 TF regardless of occupancy).
// Partials are bf16 (8 x 4MB, aliased over the dead flash-op region).
// ---------------------------------------------------------------------------
__global__ __launch_bounds__(256) void sgconv_gemm8(
    const bf16_t* __restrict__ sgb, const bf16_t* __restrict__ aot,
    bf16_t* __restrict__ o2p)
{
    const int i = blockIdx.x & 127;          // 32 m-blocks x 4 n-blocks
    const int kb = blockIdx.x >> 7;          // 8 K-chunks of 512
    const int m0 = (i & 31) * 128, n0 = (i >> 5) * 128;
    const int kbase = kb * 512;
    gemm_body128<bf16_t>(sgb + kbase, 4096, aot + kbase, 4096, nullptr, nullptr, 1.f,
                         o2p + (size_t)kb * ((size_t)4096 * 512), 512, 512, m0, n0);
}

// sum 8 bf16 partials -> bf16 o2 (one pass, coalesced; 36MB traffic ~6us)
__global__ __launch_bounds__(256) void part_reduce8(
    const bf16_t* __restrict__ p, bf16_t* __restrict__ o2)
{
    const size_t S = (size_t)4096 * 512;
    const size_t idx = ((size_t)blockIdx.x * 256 + threadIdx.x) * 8;
    float s[8] = {};
#pragma unroll
    for (int kb = 0; kb < 8; ++kb) {
        bf16x8 v = *(const bf16x8*)(p + kb * S + idx);
#pragma unroll
        for (int j = 0; j < 8; ++j) s[j] += (float)v[j];
    }
    uint4 u;
    u.x = pack_bf2(s[0], s[1]);
    u.y = pack_bf2(s[2], s[3]);
    u.z = pack_bf2(s[4], s[5]);
    u.w = pack_bf2(s[6], s[7]);
    *(uint4*)(o2 + idx) = u;
}

// out = o2 @ Wo^T + bo. TM=TN=64 (wave tile 32x32) -> grid 512 = 2 blocks/CU.
__global__ __launch_bounds__(256) void out_proj(
    const bf16_t* __restrict__ o2, const bf16_t* __restrict__ woB,
    const float* __restrict__ bo, float* __restrict__ out)
{
    const int i = blockIdx.x, x = i & 7, t = i >> 3;
    const int n0 = (t & 7) * 64;
    const int m0 = ((t >> 3) * 8 + x) * 64;

    __shared__ bf16_t As[64 * 68];
    __shared__ bf16_t Bs[64 * 68];

    const int tid = threadIdx.x;
    const int lane = tid & 63, wave = tid >> 6;
    const int wm = wave & 1, wn = wave >> 1;
    const int lo16 = lane & 15, quad = lane >> 4;
    const int sr = tid >> 2, sc = (tid & 3) * 8;

    floatx4 acc[2][2] = {};

    for (int k0 = 0; k0 < 512; k0 += 32) {
        bf16x8 a0 = *(const bf16x8*)(o2 + (size_t)(m0 + sr) * 512 + k0 + sc);
        bf16x8 b0 = *(const bf16x8*)(woB + (size_t)(n0 + sr) * 512 + k0 + sc);
        __syncthreads();
        *(bf16x8*)(&As[sr * 68 + sc]) = a0;
        *(bf16x8*)(&Bs[sr * 68 + sc]) = b0;
        __syncthreads();

        bf16x8 af[2], bfv[2];
#pragma unroll
        for (int mt = 0; mt < 2; ++mt)
            af[mt] = *(const bf16x8*)(&As[(wm * 32 + mt * 16 + lo16) * 68 + quad * 8]);
#pragma unroll
        for (int nt = 0; nt < 2; ++nt)
            bfv[nt] = *(const bf16x8*)(&Bs[(wn * 32 + nt * 16 + lo16) * 68 + quad * 8]);
#pragma unroll
        for (int mt = 0; mt < 2; ++mt)
#pragma unroll
            for (int nt = 0; nt < 2; ++nt)
                acc[mt][nt] = __builtin_amdgcn_mfma_f32_16x16x32_bf16(
                    af[mt], bfv[nt], acc[mt][nt], 0, 0, 0);
    }

#pragma unroll
    for (int nt = 0; nt < 2; ++nt) {
        const int gn = n0 + wn * 32 + nt * 16 + lo16;
        const float bc = bo[gn];
#pragma unroll
        for (int mt = 0; mt < 2; ++mt)
#pragma unroll
            for (int r = 0; r < 4; ++r) {
                const int gm = m0 + wm * 32 + mt * 16 + quad * 4 + r;
                out[(size_t)gm * 512 + gn] = acc[mt][nt][r] + bc;
            }
    }
}

// ---------------------------------------------------------------------------
// Flash attention. Pure 1024-block grid (4 blocks/CU).
// Q comes in pre-scaled by (1/sqrt(D))*log2(e) -> bare v_exp_f32.
// Softmax denominator accumulated via ones-operand MFMA.
// (setprio removed: r4 measured 52.6->53.5 regression; r10/r11 confirm 52.9.)
// ---------------------------------------------------------------------------
__global__ __launch_bounds__(256, 4) void flash_attn(
    const bf16_t* __restrict__ q, const bf16_t* __restrict__ kk,
    const bf16_t* __restrict__ vt, float* __restrict__ op,
    float* __restrict__ lp)
{
    const int fid = blockIdx.x;

    const int N = 4096, D = 512;
    const int h   = fid & 7;
    const int qb  = (fid >> 3) & 31;
    const int qtr = fid >> 8;
    const int t0  = qtr * 1024;

    const int tid = threadIdx.x;
    const int w = tid >> 6, lane = tid & 63;
    const int lo16 = lane & 15, quad = lane >> 4;

    __shared__ bf16_t Ks[64 * 72];
    __shared__ bf16_t Vs[64 * 72];
    __shared__ bf16_t Ps[4][32 * 72];

    const bf16_t* qp = q + (size_t)(qb * 128 + w * 32 + lo16) * D + h * 64 + quad * 8;
    bf16x8 qf[2][2];
    qf[0][0] = *(const bf16x8*)qp;
    qf[0][1] = *(const bf16x8*)(qp + 32);
    qf[1][0] = *(const bf16x8*)(qp + 16 * D);
    qf[1][1] = *(const bf16x8*)(qp + 16 * D + 32);

    const int srow = tid >> 2, sc = (tid & 3) * 16;
    const bf16_t* ksrc = kk + (size_t)(t0 + srow) * D + h * 64 + sc;
    const bf16_t* vsrc = vt + (size_t)(h * 64 + srow) * N + t0 + sc;
    bf16_t* kdst = &Ks[srow * 72 + sc];
    bf16_t* vdst = &Vs[srow * 72 + sc];

    bf16x8 ones;
#pragma unroll
    for (int i = 0; i < 8; ++i) ones[i] = (bf16_t)1.0f;

    floatx4 o[4][2] = {};
    floatx4 lacc[2] = {};

    bf16x8 kr0 = *(const bf16x8*)ksrc;
    bf16x8 kr1 = *(const bf16x8*)(ksrc + 8);
    bf16x8 vr0 = *(const bf16x8*)vsrc;
    bf16x8 vr1 = *(const bf16x8*)(vsrc + 8);

    for (int it = 0; it < 16; ++it) {
        __syncthreads();
        *(bf16x8*)kdst = kr0;  *(bf16x8*)(kdst + 8) = kr1;
        *(bf16x8*)vdst = vr0;  *(bf16x8*)(vdst + 8) = vr1;
        __syncthreads();
        if (it < 15) {
            const bf16_t* kn = ksrc + (size_t)(it + 1) * 64 * D;
            const bf16_t* vn = vsrc + (it + 1) * 64;
            kr0 = *(const bf16x8*)kn;  kr1 = *(const bf16x8*)(kn + 8);
            vr0 = *(const bf16x8*)vn;  vr1 = *(const bf16x8*)(vn + 8);
        }

        // S^T = K·Q^T : D[m=tok][n=q]
        floatx4 s[4][2];
#pragma unroll
        for (int tt = 0; tt < 4; ++tt) {
            bf16x8 kf0 = *(const bf16x8*)(&Ks[(tt * 16 + lo16) * 72 + quad * 8]);
            bf16x8 kf1 = *(const bf16x8*)(&Ks[(tt * 16 + lo16) * 72 + 32 + quad * 8]);
#pragma unroll
            for (int qt = 0; qt < 2; ++qt) {
                floatx4 a = {};
                a = __builtin_amdgcn_mfma_f32_16x16x32_bf16(kf0, qf[qt][0], a, 0, 0, 0);
                a = __builtin_amdgcn_mfma_f32_16x16x32_bf16(kf1, qf[qt][1], a, 0, 0, 0);
                s[tt][qt] = a;
            }
        }
        // exp2 + packed b64 P writes (row sums come from the ones-MFMA below)
#pragma unroll
        for (int tt = 0; tt < 4; ++tt)
#pragma unroll
            for (int qt = 0; qt < 2; ++qt) {
                float e0 = __builtin_amdgcn_exp2f(s[tt][qt][0]);
                float e1 = __builtin_amdgcn_exp2f(s[tt][qt][1]);
                float e2 = __builtin_amdgcn_exp2f(s[tt][qt][2]);
                float e3 = __builtin_amdgcn_exp2f(s[tt][qt][3]);
                uint2 pk;
                pk.x = pack_bf2(e0, e1);
                pk.y = pack_bf2(e2, e3);
                *(uint2*)(&Ps[w][(qt * 16 + lo16) * 72 + tt * 16 + quad * 4]) = pk;
            }
        // PV: o[dim][q] += V·P^T ; l[q] += 1·P^T (denominator via MFMA)
#pragma unroll
        for (int ks = 0; ks < 2; ++ks) {
            bf16x8 pf0 = *(const bf16x8*)(&Ps[w][lo16 * 72 + ks * 32 + quad * 8]);
            bf16x8 pf1 = *(const bf16x8*)(&Ps[w][(16 + lo16) * 72 + ks * 32 + quad * 8]);
            lacc[0] = __builtin_amdgcn_mfma_f32_16x16x32_bf16(ones, pf0, lacc[0], 0, 0, 0);
            lacc[1] = __builtin_amdgcn_mfma_f32_16x16x32_bf16(ones, pf1, lacc[1], 0, 0, 0);
#pragma unroll
            for (int t = 0; t < 4; ++t) {
                bf16x8 vf = *(const bf16x8*)(&Vs[(t * 16 + lo16) * 72 + ks * 32 + quad * 8]);
                o[t][0] = __builtin_amdgcn_mfma_f32_16x16x32_bf16(vf, pf0, o[t][0], 0, 0, 0);
                o[t][1] = __builtin_amdgcn_mfma_f32_16x16x32_bf16(vf, pf1, o[t][1], 0, 0, 0);
            }
        }
    }

    const int g = fid & 255;
    float* opw = op + ((size_t)qtr * 256 + g) * 8192;
#pragma unroll
    for (int t = 0; t < 4; ++t)
#pragma unroll
        for (int pt = 0; pt < 2; ++pt)
#pragma unroll
            for (int r = 0; r < 4; ++r)
                opw[(t * 16 + quad * 4 + r) * 128 + w * 32 + pt * 16 + lo16] = o[t][pt][r];

    if (quad == 0) {   // all 4 lacc rows identical (ones A-operand); take r=0
        float* lpw = lp + ((size_t)qtr * 256 + g) * 128;
        lpw[w * 32 + lo16] = lacc[0][0];
        lpw[w * 32 + 16 + lo16] = lacc[1][0];
    }
}

// grid 1024 (4/CU): bid = (g, quarter). Each block does 2048 of the 8192 elems.
__global__ __launch_bounds__(256) void attn_combine(
    const float* __restrict__ op, const float* __restrict__ lp, bf16_t* __restrict__ aot)
{
    const int bid = blockIdx.x;
    const int g = bid >> 2, qu = bid & 3;
    const int h = g & 7, qb = g >> 3;
    const int tid = threadIdx.x;
    __shared__ float ls[128];
    if (tid < 128) {
        float s = 0.f;
#pragma unroll
        for (int qtr = 0; qtr < 4; ++qtr)
            s += lp[((size_t)qtr * 256 + g) * 128 + tid];
        ls[tid] = 1.0f / s;
    }
    __syncthreads();
    const float* b0 = op + (size_t)g * 8192;
    const size_t QS = (size_t)256 * 8192;
#pragma unroll
    for (int i = 0; i < 8; ++i) {
        int idx = qu * 2048 + i * 256 + tid;
        float v = b0[idx] + b0[QS + idx] + b0[2 * QS + idx] + b0[3 * QS + idx];
        int dim = idx >> 7, qc = idx & 127;
        aot[(size_t)(h * 64 + dim) * 4096 + qb * 128 + qc] = (bf16_t)(v * ls[qc]);
    }
}

extern "C" void kernel_launch(void* const* d_in, const int* in_sizes, int n_in,
                              void* d_out, int out_size, void* d_ws, size_t ws_size,
                              hipStream_t stream)
{
    const int N = 4096, D = 512;
    const float* query = (const float*)d_in[0];
    const float* key_t = (const float*)d_in[1];
    const float* value = (const float*)d_in[2];
    const float* Wq = (const float*)d_in[3];
    const float* bq = (const float*)d_in[4];
    const float* Wk = (const float*)d_in[5];
    const float* bk = (const float*)d_in[6];
    const float* Wv = (const float*)d_in[7];
    const float* bv = (const float*)d_in[8];
    const float* Wo = (const float*)d_in[9];
    const float* bo = (const float*)d_in[10];
    const float* sg = (const float*)d_in[11];
    float* out = (float*)d_out;

    const size_t ND = (size_t)N * D;
    const size_t DD = (size_t)D * D;

    char* base = (char*)d_ws;
    bf16_t* q    = (bf16_t*)base;
    bf16_t* kk   = q   + ND;
    bf16_t* vt   = kk  + ND;
    bf16_t* aot  = vt  + ND;
    bf16_t* sgb  = aot + ND;
    char* regA   = (char*)(sgb + (size_t)N * N);
    // region A, phase 1: prep inputs (13.5MB)
    bf16_t* qB   = (bf16_t*)regA;
    bf16_t* kB   = qB + ND;
    bf16_t* vB   = kB + ND;
    bf16_t* wqB  = vB + ND;
    bf16_t* wkB  = wqB + DD;
    bf16_t* wvB  = wkB + DD;
    // region A, phase 2: flash partials op (32MB); phase 3: sgconv bf16 partials (32MB)
    float* op    = (float*)regA;
    bf16_t* o2p  = (bf16_t*)regA;
    char* tail   = regA + (size_t)4 * 256 * 8192 * 4;   // 32MB
    float*  lp   = (float*)tail;
    bf16_t* woB  = (bf16_t*)(lp + (size_t)4 * 256 * 128);
    bf16_t* o2   = woB + DD;

    const dim3 blk(256);

    prep<<<896, blk, 0, stream>>>(query, key_t, value, Wq, Wk, Wv, Wo,
                                  qB, kB, vB, wqB, wkB, wvB, woB);

    const float qscale = 1.44269504088896f / sqrtf((float)D);
    proj_qkv<<<2432, blk, 0, stream>>>(qB, wqB, bq, kB, wkB, bk,
                                       wvB, vB, bv, q, kk, vt, qscale, sg, sgb);

    flash_attn<<<1024, blk, 0, stream>>>(q, kk, vt, op, lp);
    attn_combine<<<1024, blk, 0, stream>>>(op, lp, aot);

    sgconv_gemm8<<<1024, blk, 0, stream>>>(sgb, aot, o2p);
    part_reduce8<<<1024, blk, 0, stream>>>(o2p, o2);
    out_proj<<<512, blk, 0, stream>>>(o2, woB, bo, out);

    (void)in_sizes; (void)n_in; (void)out_size; (void)ws_size;
}

// Round 16
// 256.647 us; speedup vs baseline: 1.0112x; 1.0112x over previous
//
#include <hip/hip_runtime.h>
#include <hip/hip_bf16.h>
#include <math.h>

typedef __bf16 bf16_t;
typedef __bf16 bf16x8 __attribute__((ext_vector_type(8)));
typedef float floatx4 __attribute__((ext_vector_type(4)));

typedef __attribute__((address_space(1))) void gvoid_t;
typedef __attribute__((address_space(3))) void lvoid_t;

// Async 16B/lane global->LDS. Pass the WAVE-UNIFORM LDS base; HW writes lane l
// at base + l*16. Global address is per-lane. (inttoptr as3 = low-32 LDS offset.)
static __device__ __forceinline__ void gload_lds16(const bf16_t* g, const bf16_t* l) {
    __builtin_amdgcn_global_load_lds((gvoid_t*)(size_t)g,
                                     (lvoid_t*)(unsigned)(size_t)l,
                                     16, 0, 0);
}

// native RNE f32->bf16 pair pack (compiler emits v_cvt_pk_bf16_f32)
static __device__ __forceinline__ unsigned pack_bf2(float lo, float hi) {
    bf16_t a = (bf16_t)lo, b = (bf16_t)hi;
    return (unsigned)__builtin_bit_cast(unsigned short, a)
         | ((unsigned)__builtin_bit_cast(unsigned short, b) << 16);
}

static __device__ inline void store_c(float* C, size_t i, float v) { C[i] = v; }
static __device__ inline void store_c(bf16_t* C, size_t i, float v) { C[i] = (bf16_t)v; }

// elementwise bf16x8 add (via f32)
static __device__ __forceinline__ bf16x8 add8(bf16x8 a, bf16x8 b) {
    bf16x8 r;
#pragma unroll
    for (int i = 0; i < 8; ++i) r[i] = (bf16_t)((float)a[i] + (float)b[i]);
    return r;
}

// convert 8 fp32 -> 8 bf16 (16B store)
static __device__ inline void cvt8(const float* src, bf16_t* dst, size_t idx) {
    float4 a = *(const float4*)(src + idx);
    float4 c = *(const float4*)(src + idx + 4);
    uint4 u;
    u.x = pack_bf2(a.x, a.y);
    u.y = pack_bf2(a.z, a.w);
    u.z = pack_bf2(c.x, c.y);
    u.w = pack_bf2(c.z, c.w);
    *(uint4*)(dst + idx) = u;
}

// ---------------------------------------------------------------------------
// m97-class GEMM body: C = (A[M,K]*B[N,K]^T (+bias_col)(+bias_row)) * cscale.
// TM=TN=128, BK=32, 4 waves (2x2), 4x4 16x16x32 fragments per wave.
// Staging via global_load_lds (linear LDS); bank conflicts broken by XOR-
// swizzling the 16B chunk index with ((row>>1)&3) on BOTH the global source
// address (write side is linear) and the ds_read address.
// (setprio removed: r4 A/B showed it regresses this lockstep structure, m190.)
// ---------------------------------------------------------------------------
template <typename TC>
__device__ inline void gemm_body128(
    const bf16_t* __restrict__ A, int lda,
    const bf16_t* __restrict__ B, int ldb,
    const float* __restrict__ bias_col, const float* __restrict__ bias_row,
    float cscale,
    TC* __restrict__ C, int ldc, int K, int m0, int n0)
{
    __shared__ bf16_t As[128 * 32];
    __shared__ bf16_t Bs[128 * 32];

    const int tid = threadIdx.x;
    const int lane = tid & 63, wave = tid >> 6;
    const int wm = wave & 1, wn = wave >> 1;
    const int lo16 = lane & 15, quad = lane >> 4;

    // staging map: thread covers (row = i*64 + tid/4, 16B chunk slot = tid%4)
    const int r0 = tid >> 2;
    const int s0 = tid & 3;
    const int c0 = s0 ^ ((r0 >> 1) & 3);   // ((64+r0)>>1)&3 == (r0>>1)&3, same chunk both issues
    const bf16_t* ga0 = A + (size_t)(m0 + r0) * lda + c0 * 8;
    const bf16_t* ga1 = A + (size_t)(m0 + 64 + r0) * lda + c0 * 8;
    const bf16_t* gb0 = B + (size_t)(n0 + r0) * ldb + c0 * 8;
    const bf16_t* gb1 = B + (size_t)(n0 + 64 + r0) * ldb + c0 * 8;
    const bf16_t* la0 = As + wave * 512;           // wave-uniform LDS bases
    const bf16_t* la1 = As + 2048 + wave * 512;
    const bf16_t* lb0 = Bs + wave * 512;
    const bf16_t* lb1 = Bs + 2048 + wave * 512;

    // swizzled fragment read offsets (elems), precomputed
    int aoff[4], boff[4];
#pragma unroll
    for (int t = 0; t < 4; ++t) {
        const int ra = wm * 64 + t * 16 + lo16;
        aoff[t] = ra * 32 + ((quad ^ ((ra >> 1) & 3)) << 3);
        const int rb = wn * 64 + t * 16 + lo16;
        boff[t] = rb * 32 + ((quad ^ ((rb >> 1) & 3)) << 3);
    }

    floatx4 acc[4][4] = {};

    for (int k0 = 0; k0 < K; k0 += 32) {
        __syncthreads();                 // prev ds_reads done before overwrite
        gload_lds16(ga0 + k0, la0);
        gload_lds16(ga1 + k0, la1);
        gload_lds16(gb0 + k0, lb0);
        gload_lds16(gb1 + k0, lb1);
        __syncthreads();                 // compiler drains vmcnt(0) before barrier

        bf16x8 af[4], bfv[4];
#pragma unroll
        for (int t = 0; t < 4; ++t) {
            af[t]  = *(const bf16x8*)(As + aoff[t]);
            bfv[t] = *(const bf16x8*)(Bs + boff[t]);
        }
#pragma unroll
        for (int mt = 0; mt < 4; ++mt)
#pragma unroll
            for (int nt = 0; nt < 4; ++nt)
                acc[mt][nt] = __builtin_amdgcn_mfma_f32_16x16x32_bf16(
                    af[mt], bfv[nt], acc[mt][nt], 0, 0, 0);
    }

#pragma unroll
    for (int nt = 0; nt < 4; ++nt) {
        const int gn = n0 + wn * 64 + nt * 16 + lo16;
        const float bc = bias_col ? bias_col[gn] : 0.f;
#pragma unroll
        for (int mt = 0; mt < 4; ++mt) {
#pragma unroll
            for (int r = 0; r < 4; ++r) {
                const int gm = m0 + wm * 64 + mt * 16 + quad * 4 + r;
                float v = acc[mt][nt][r] + bc;
                if (bias_row) v += bias_row[gm];
                store_c(C, (size_t)gm * ldc + gn, v * cscale);
            }
        }
    }
}

// Bulk fp32->bf16: q/k/v inputs, 4 weight matrices, AND the sg matrix.
// All streaming blocks share one low-VGPR, no-LDS kernel -> high occupancy
// (r12 lesson: converts inside the 132-VGPR proj kernel ran at 1.6TB/s, 20%).
// grid 2944: 896 input/weight blocks + 2048 sg blocks, 8192 elems each.
__global__ __launch_bounds__(256) void prep(
    const float* __restrict__ query, const float* __restrict__ key, const float* __restrict__ value,
    const float* __restrict__ Wq, const float* __restrict__ Wk,
    const float* __restrict__ Wv, const float* __restrict__ Wo,
    const float* __restrict__ sg,
    bf16_t* qB, bf16_t* kB, bf16_t* vB,
    bf16_t* wqB, bf16_t* wkB, bf16_t* wvB, bf16_t* woB,
    bf16_t* sgb)
{
    const int b = blockIdx.x;
    const float* src; bf16_t* dst; size_t base;
    if      (b < 256) { src = query; dst = qB;  base = (size_t)b * 8192; }
    else if (b < 512) { src = key;   dst = kB;  base = (size_t)(b - 256) * 8192; }
    else if (b < 768) { src = value; dst = vB;  base = (size_t)(b - 512) * 8192; }
    else if (b < 800) { src = Wq;    dst = wqB; base = (size_t)(b - 768) * 8192; }
    else if (b < 832) { src = Wk;    dst = wkB; base = (size_t)(b - 800) * 8192; }
    else if (b < 864) { src = Wv;    dst = wvB; base = (size_t)(b - 832) * 8192; }
    else if (b < 896) { src = Wo;    dst = woB; base = (size_t)(b - 864) * 8192; }
    else              { src = sg;    dst = sgb; base = (size_t)(b - 896) * 8192; }
#pragma unroll
    for (int it = 0; it < 4; ++it)
        cvt8(src, dst, base + (size_t)it * 2048 + threadIdx.x * 8);
}

// QKV projections ONLY: 3 GEMMs x 128 blocks (128x128 tiles) = 384 blocks.
// Q output is pre-scaled by (1/sqrt(D))*log2(e) so flash can use a bare exp2.
__global__ __launch_bounds__(256) void proj_qkv(
    const bf16_t* __restrict__ qB, const bf16_t* __restrict__ wqB, const float* __restrict__ bq,
    const bf16_t* __restrict__ kB, const bf16_t* __restrict__ wkB, const float* __restrict__ bk,
    const bf16_t* __restrict__ wvB, const bf16_t* __restrict__ vB, const float* __restrict__ bv,
    bf16_t* __restrict__ q, bf16_t* __restrict__ k, bf16_t* __restrict__ vt, float qscale)
{
    const int b = blockIdx.x;
    const int i = b & 127;
    if (b < 256) {
        const int m0 = (i & 31) * 128, n0 = (i >> 5) * 128;  // M=4096, N=512
        if (b < 128)
            gemm_body128<bf16_t>(qB, 512, wqB, 512, bq, nullptr, qscale, q, 512, 512, m0, n0);
        else
            gemm_body128<bf16_t>(kB, 512, wkB, 512, bk, nullptr, 1.f, k, 512, 512, m0, n0);
    } else {
        const int m0 = (i & 3) * 128, n0 = (i >> 2) * 128;   // M=512, N=4096 (vt transposed)
        gemm_body128<bf16_t>(wvB, 512, vB, 512, nullptr, bv, 1.f, vt, 4096, 512, m0, n0);
    }
}

// ---------------------------------------------------------------------------
// sgconv, 2-way K-split (r11 measured-best): o2p[kb] = partial over K-half kb.
// 64x64 tiles, K=2048/block -> grid 1024 = 4 blocks/CU. bf16 partials (8MB);
// out_proj sums the two halves during A-staging.
// ---------------------------------------------------------------------------
__global__ __launch_bounds__(256) void sgconv_half(
    const bf16_t* __restrict__ sgb, const bf16_t* __restrict__ aot,
    bf16_t* __restrict__ o2p)
{
    const int bid = blockIdx.x;
    const int i = bid & 511;
    const int kb = bid >> 9;          // 0 or 1
    const int m0 = (i & 63) * 64;     // token rows
    const int n0 = (i >> 6) * 64;     // dim cols
    const int kbase = kb * 2048;

    __shared__ bf16_t As[64 * 64];
    __shared__ bf16_t Bs[64 * 64];

    const int tid = threadIdx.x;
    const int lane = tid & 63, wave = tid >> 6;
    const int wm = wave & 1, wn = wave >> 1;
    const int lo16 = lane & 15, quad = lane >> 4;

    // staging: issue j covers rows j*32 + tid/8; chunk slot tid&7, src chunk XOR'd
    const int r0 = tid >> 3, s0 = tid & 7;
    const int c0 = s0 ^ (r0 & 7);          // rows +32 keep the same (row&7)
    const bf16_t* gaA = sgb + (size_t)(m0 + r0) * 4096 + kbase + c0 * 8;
    const bf16_t* gaB = aot + (size_t)(n0 + r0) * 4096 + kbase + c0 * 8;
    const bf16_t* laA0 = As + wave * 512;           // 8 rows x 64 per wave
    const bf16_t* laA1 = As + 2048 + wave * 512;
    const bf16_t* laB0 = Bs + wave * 512;
    const bf16_t* laB1 = Bs + 2048 + wave * 512;

    // swizzled fragment read offsets (elems)
    int aoff[2][2], boff[2][2];
#pragma unroll
    for (int t = 0; t < 2; ++t)
#pragma unroll
        for (int kk = 0; kk < 2; ++kk) {
            const int ra = wm * 32 + t * 16 + lo16;
            aoff[t][kk] = ra * 64 + (((kk * 4 + quad) ^ (ra & 7)) << 3);
            const int rb = wn * 32 + t * 16 + lo16;
            boff[t][kk] = rb * 64 + (((kk * 4 + quad) ^ (rb & 7)) << 3);
        }

    floatx4 acc[2][2] = {};

    for (int k0 = 0; k0 < 2048; k0 += 64) {
        __syncthreads();
        gload_lds16(gaA + k0, laA0);
        gload_lds16(gaA + (size_t)32 * 4096 + k0, laA1);
        gload_lds16(gaB + k0, laB0);
        gload_lds16(gaB + (size_t)32 * 4096 + k0, laB1);
        __syncthreads();

        bf16x8 af[2][2], bfv[2][2];
#pragma unroll
        for (int t = 0; t < 2; ++t)
#pragma unroll
            for (int kk = 0; kk < 2; ++kk) {
                af[t][kk]  = *(const bf16x8*)(As + aoff[t][kk]);
                bfv[t][kk] = *(const bf16x8*)(Bs + boff[t][kk]);
            }
#pragma unroll
        for (int mt = 0; mt < 2; ++mt)
#pragma unroll
            for (int nt = 0; nt < 2; ++nt)
#pragma unroll
                for (int kk = 0; kk < 2; ++kk)
                    acc[mt][nt] = __builtin_amdgcn_mfma_f32_16x16x32_bf16(
                        af[mt][kk], bfv[nt][kk], acc[mt][nt], 0, 0, 0);
    }

    bf16_t* dst = o2p + (size_t)kb * ((size_t)4096 * 512);
#pragma unroll
    for (int nt = 0; nt < 2; ++nt) {
        const int gn = n0 + wn * 32 + nt * 16 + lo16;
#pragma unroll
        for (int mt = 0; mt < 2; ++mt)
#pragma unroll
            for (int r = 0; r < 4; ++r) {
                const int gm = m0 + wm * 32 + mt * 16 + quad * 4 + r;
                dst[(size_t)gm * 512 + gn] = (bf16_t)acc[mt][nt][r];
            }
    }
}

// out = (o2a+o2b) @ Wo^T + bo. TM=TN=64 (wave tile 32x32) -> grid 512 = 2/CU.
// The two sgconv K-half partials are summed during A-staging.
__global__ __launch_bounds__(256) void out_proj(
    const bf16_t* __restrict__ o2a, const bf16_t* __restrict__ o2b,
    const bf16_t* __restrict__ woB,
    const float* __restrict__ bo, float* __restrict__ out)
{
    const int i = blockIdx.x, x = i & 7, t = i >> 3;
    const int n0 = (t & 7) * 64;
    const int m0 = ((t >> 3) * 8 + x) * 64;

    __shared__ bf16_t As[64 * 68];
    __shared__ bf16_t Bs[64 * 68];

    const int tid = threadIdx.x;
    const int lane = tid & 63, wave = tid >> 6;
    const int wm = wave & 1, wn = wave >> 1;
    const int lo16 = lane & 15, quad = lane >> 4;
    const int sr = tid >> 2, sc = (tid & 3) * 8;

    floatx4 acc[2][2] = {};

    for (int k0 = 0; k0 < 512; k0 += 32) {
        const size_t aidx = (size_t)(m0 + sr) * 512 + k0 + sc;
        bf16x8 a0 = add8(*(const bf16x8*)(o2a + aidx), *(const bf16x8*)(o2b + aidx));
        bf16x8 b0 = *(const bf16x8*)(woB + (size_t)(n0 + sr) * 512 + k0 + sc);
        __syncthreads();
        *(bf16x8*)(&As[sr * 68 + sc]) = a0;
        *(bf16x8*)(&Bs[sr * 68 + sc]) = b0;
        __syncthreads();

        bf16x8 af[2], bfv[2];
#pragma unroll
        for (int mt = 0; mt < 2; ++mt)
            af[mt] = *(const bf16x8*)(&As[(wm * 32 + mt * 16 + lo16) * 68 + quad * 8]);
#pragma unroll
        for (int nt = 0; nt < 2; ++nt)
            bfv[nt] = *(const bf16x8*)(&Bs[(wn * 32 + nt * 16 + lo16) * 68 + quad * 8]);
#pragma unroll
        for (int mt = 0; mt < 2; ++mt)
#pragma unroll
            for (int nt = 0; nt < 2; ++nt)
                acc[mt][nt] = __builtin_amdgcn_mfma_f32_16x16x32_bf16(
                    af[mt], bfv[nt], acc[mt][nt], 0, 0, 0);
    }

#pragma unroll
    for (int nt = 0; nt < 2; ++nt) {
        const int gn = n0 + wn * 32 + nt * 16 + lo16;
        const float bc = bo[gn];
#pragma unroll
        for (int mt = 0; mt < 2; ++mt)
#pragma unroll
            for (int r = 0; r < 4; ++r) {
                const int gm = m0 + wm * 32 + mt * 16 + quad * 4 + r;
                out[(size_t)gm * 512 + gn] = acc[mt][nt][r] + bc;
            }
    }
}

// ---------------------------------------------------------------------------
// Flash attention. Pure 1024-block grid (4 blocks/CU).
// Q comes in pre-scaled by (1/sqrt(D))*log2(e) -> bare v_exp_f32.
// Softmax denominator accumulated via ones-operand MFMA.
// (setprio removed: r4 measured 52.6->53.5 regression; r10/r11 confirm 52.9.)
// ---------------------------------------------------------------------------
__global__ __launch_bounds__(256, 4) void flash_attn(
    const bf16_t* __restrict__ q, const bf16_t* __restrict__ kk,
    const bf16_t* __restrict__ vt, float* __restrict__ op,
    float* __restrict__ lp)
{
    const int fid = blockIdx.x;

    const int N = 4096, D = 512;
    const int h   = fid & 7;
    const int qb  = (fid >> 3) & 31;
    const int qtr = fid >> 8;
    const int t0  = qtr * 1024;

    const int tid = threadIdx.x;
    const int w = tid >> 6, lane = tid & 63;
    const int lo16 = lane & 15, quad = lane >> 4;

    __shared__ bf16_t Ks[64 * 72];
    __shared__ bf16_t Vs[64 * 72];
    __shared__ bf16_t Ps[4][32 * 72];

    const bf16_t* qp = q + (size_t)(qb * 128 + w * 32 + lo16) * D + h * 64 + quad * 8;
    bf16x8 qf[2][2];
    qf[0][0] = *(const bf16x8*)qp;
    qf[0][1] = *(const bf16x8*)(qp + 32);
    qf[1][0] = *(const bf16x8*)(qp + 16 * D);
    qf[1][1] = *(const bf16x8*)(qp + 16 * D + 32);

    const int srow = tid >> 2, sc = (tid & 3) * 16;
    const bf16_t* ksrc = kk + (size_t)(t0 + srow) * D + h * 64 + sc;
    const bf16_t* vsrc = vt + (size_t)(h * 64 + srow) * N + t0 + sc;
    bf16_t* kdst = &Ks[srow * 72 + sc];
    bf16_t* vdst = &Vs[srow * 72 + sc];

    bf16x8 ones;
#pragma unroll
    for (int i = 0; i < 8; ++i) ones[i] = (bf16_t)1.0f;

    floatx4 o[4][2] = {};
    floatx4 lacc[2] = {};

    bf16x8 kr0 = *(const bf16x8*)ksrc;
    bf16x8 kr1 = *(const bf16x8*)(ksrc + 8);
    bf16x8 vr0 = *(const bf16x8*)vsrc;
    bf16x8 vr1 = *(const bf16x8*)(vsrc + 8);

    for (int it = 0; it < 16; ++it) {
        __syncthreads();
        *(bf16x8*)kdst = kr0;  *(bf16x8*)(kdst + 8) = kr1;
        *(bf16x8*)vdst = vr0;  *(bf16x8*)(vdst + 8) = vr1;
        __syncthreads();
        if (it < 15) {
            const bf16_t* kn = ksrc + (size_t)(it + 1) * 64 * D;
            const bf16_t* vn = vsrc + (it + 1) * 64;
            kr0 = *(const bf16x8*)kn;  kr1 = *(const bf16x8*)(kn + 8);
            vr0 = *(const bf16x8*)vn;  vr1 = *(const bf16x8*)(vn + 8);
        }

        // S^T = K·Q^T : D[m=tok][n=q]
        floatx4 s[4][2];
#pragma unroll
        for (int tt = 0; tt < 4; ++tt) {
            bf16x8 kf0 = *(const bf16x8*)(&Ks[(tt * 16 + lo16) * 72 + quad * 8]);
            bf16x8 kf1 = *(const bf16x8*)(&Ks[(tt * 16 + lo16) * 72 + 32 + quad * 8]);
#pragma unroll
            for (int qt = 0; qt < 2; ++qt) {
                floatx4 a = {};
                a = __builtin_amdgcn_mfma_f32_16x16x32_bf16(kf0, qf[qt][0], a, 0, 0, 0);
                a = __builtin_amdgcn_mfma_f32_16x16x32_bf16(kf1, qf[qt][1], a, 0, 0, 0);
                s[tt][qt] = a;
            }
        }
        // exp2 + packed b64 P writes (row sums come from the ones-MFMA below)
#pragma unroll
        for (int tt = 0; tt < 4; ++tt)
#pragma unroll
            for (int qt = 0; qt < 2; ++qt) {
                float e0 = __builtin_amdgcn_exp2f(s[tt][qt][0]);
                float e1 = __builtin_amdgcn_exp2f(s[tt][qt][1]);
                float e2 = __builtin_amdgcn_exp2f(s[tt][qt][2]);
                float e3 = __builtin_amdgcn_exp2f(s[tt][qt][3]);
                uint2 pk;
                pk.x = pack_bf2(e0, e1);
                pk.y = pack_bf2(e2, e3);
                *(uint2*)(&Ps[w][(qt * 16 + lo16) * 72 + tt * 16 + quad * 4]) = pk;
            }
        // PV: o[dim][q] += V·P^T ; l[q] += 1·P^T (denominator via MFMA)
#pragma unroll
        for (int ks = 0; ks < 2; ++ks) {
            bf16x8 pf0 = *(const bf16x8*)(&Ps[w][lo16 * 72 + ks * 32 + quad * 8]);
            bf16x8 pf1 = *(const bf16x8*)(&Ps[w][(16 + lo16) * 72 + ks * 32 + quad * 8]);
            lacc[0] = __builtin_amdgcn_mfma_f32_16x16x32_bf16(ones, pf0, lacc[0], 0, 0, 0);
            lacc[1] = __builtin_amdgcn_mfma_f32_16x16x32_bf16(ones, pf1, lacc[1], 0, 0, 0);
#pragma unroll
            for (int t = 0; t < 4; ++t) {
                bf16x8 vf = *(const bf16x8*)(&Vs[(t * 16 + lo16) * 72 + ks * 32 + quad * 8]);
                o[t][0] = __builtin_amdgcn_mfma_f32_16x16x32_bf16(vf, pf0, o[t][0], 0, 0, 0);
                o[t][1] = __builtin_amdgcn_mfma_f32_16x16x32_bf16(vf, pf1, o[t][1], 0, 0, 0);
            }
        }
    }

    const int g = fid & 255;
    float* opw = op + ((size_t)qtr * 256 + g) * 8192;
#pragma unroll
    for (int t = 0; t < 4; ++t)
#pragma unroll
        for (int pt = 0; pt < 2; ++pt)
#pragma unroll
            for (int r = 0; r < 4; ++r)
                opw[(t * 16 + quad * 4 + r) * 128 + w * 32 + pt * 16 + lo16] = o[t][pt][r];

    if (quad == 0) {   // all 4 lacc rows identical (ones A-operand); take r=0
        float* lpw = lp + ((size_t)qtr * 256 + g) * 128;
        lpw[w * 32 + lo16] = lacc[0][0];
        lpw[w * 32 + 16 + lo16] = lacc[1][0];
    }
}

// grid 1024 (4/CU): bid = (g, quarter). Each block does 2048 of the 8192 elems.
__global__ __launch_bounds__(256) void attn_combine(
    const float* __restrict__ op, const float* __restrict__ lp, bf16_t* __restrict__ aot)
{
    const int bid = blockIdx.x;
    const int g = bid >> 2, qu = bid & 3;
    const int h = g & 7, qb = g >> 3;
    const int tid = threadIdx.x;
    __shared__ float ls[128];
    if (tid < 128) {
        float s = 0.f;
#pragma unroll
        for (int qtr = 0; qtr < 4; ++qtr)
            s += lp[((size_t)qtr * 256 + g) * 128 + tid];
        ls[tid] = 1.0f / s;
    }
    __syncthreads();
    const float* b0 = op + (size_t)g * 8192;
    const size_t QS = (size_t)256 * 8192;
#pragma unroll
    for (int i = 0; i < 8; ++i) {
        int idx = qu * 2048 + i * 256 + tid;
        float v = b0[idx] + b0[QS + idx] + b0[2 * QS + idx] + b0[3 * QS + idx];
        int dim = idx >> 7, qc = idx & 127;
        aot[(size_t)(h * 64 + dim) * 4096 + qb * 128 + qc] = (bf16_t)(v * ls[qc]);
    }
}

extern "C" void kernel_launch(void* const* d_in, const int* in_sizes, int n_in,
                              void* d_out, int out_size, void* d_ws, size_t ws_size,
                              hipStream_t stream)
{
    const int N = 4096, D = 512;
    const float* query = (const float*)d_in[0];
    const float* key_t = (const float*)d_in[1];
    const float* value = (const float*)d_in[2];
    const float* Wq = (const float*)d_in[3];
    const float* bq = (const float*)d_in[4];
    const float* Wk = (const float*)d_in[5];
    const float* bk = (const float*)d_in[6];
    const float* Wv = (const float*)d_in[7];
    const float* bv = (const float*)d_in[8];
    const float* Wo = (const float*)d_in[9];
    const float* bo = (const float*)d_in[10];
    const float* sg = (const float*)d_in[11];
    float* out = (float*)d_out;

    const size_t ND = (size_t)N * D;
    const size_t DD = (size_t)D * D;

    char* base = (char*)d_ws;
    bf16_t* q    = (bf16_t*)base;
    bf16_t* kk   = q   + ND;
    bf16_t* vt   = kk  + ND;
    bf16_t* aot  = vt  + ND;
    bf16_t* sgb  = aot + ND;
    char* regA   = (char*)(sgb + (size_t)N * N);
    // region A, phase 1: prep inputs (13.5MB)
    bf16_t* qB   = (bf16_t*)regA;
    bf16_t* kB   = qB + ND;
    bf16_t* vB   = kB + ND;
    bf16_t* wqB  = vB + ND;
    bf16_t* wkB  = wqB + DD;
    bf16_t* wvB  = wkB + DD;
    // region A, phase 2: flash partials op (32MB)
    float* op    = (float*)regA;
    char* tail   = regA + (size_t)4 * 256 * 8192 * 4;   // 32MB
    float*  lp   = (float*)tail;
    bf16_t* woB  = (bf16_t*)(lp + (size_t)4 * 256 * 128);
    bf16_t* o2   = woB + DD;           // two bf16 partials: 2 x 4MB
    bf16_t* o2b  = o2 + ND;

    const dim3 blk(256);

    prep<<<2944, blk, 0, stream>>>(query, key_t, value, Wq, Wk, Wv, Wo, sg,
                                   qB, kB, vB, wqB, wkB, wvB, woB, sgb);

    const float qscale = 1.44269504088896f / sqrtf((float)D);
    proj_qkv<<<384, blk, 0, stream>>>(qB, wqB, bq, kB, wkB, bk,
                                      wvB, vB, bv, q, kk, vt, qscale);

    flash_attn<<<1024, blk, 0, stream>>>(q, kk, vt, op, lp);
    attn_combine<<<1024, blk, 0, stream>>>(op, lp, aot);

    sgconv_half<<<1024, blk, 0, stream>>>(sgb, aot, o2);
    out_proj<<<512, blk, 0, stream>>>(o2, o2b, woB, bo, out);

    (void)in_sizes; (void)n_in; (void)out_size; (void)ws_size;
}

// Round 19
// 244.734 us; speedup vs baseline: 1.0604x; 1.0487x over previous
//
#include <hip/hip_runtime.h>
#include <hip/hip_bf16.h>
#include <math.h>

typedef __bf16 bf16_t;
typedef __bf16 bf16x8 __attribute__((ext_vector_type(8)));
typedef float floatx4 __attribute__((ext_vector_type(4)));

typedef __attribute__((address_space(1))) void gvoid_t;
typedef __attribute__((address_space(3))) void lvoid_t;

// Async 16B/lane global->LDS. Pass the WAVE-UNIFORM LDS base; HW writes lane l
// at base + l*16. Global address is per-lane. (inttoptr as3 = low-32 LDS offset.)
static __device__ __forceinline__ void gload_lds16(const bf16_t* g, const bf16_t* l) {
    __builtin_amdgcn_global_load_lds((gvoid_t*)(size_t)g,
                                     (lvoid_t*)(unsigned)(size_t)l,
                                     16, 0, 0);
}

// native RNE f32->bf16 pair pack (compiler emits v_cvt_pk_bf16_f32)
static __device__ __forceinline__ unsigned pack_bf2(float lo, float hi) {
    bf16_t a = (bf16_t)lo, b = (bf16_t)hi;
    return (unsigned)__builtin_bit_cast(unsigned short, a)
         | ((unsigned)__builtin_bit_cast(unsigned short, b) << 16);
}

static __device__ inline void store_c(float* C, size_t i, float v) { C[i] = v; }
static __device__ inline void store_c(bf16_t* C, size_t i, float v) { C[i] = (bf16_t)v; }

// elementwise bf16x8 add (via f32)
static __device__ __forceinline__ bf16x8 add8(bf16x8 a, bf16x8 b) {
    bf16x8 r;
#pragma unroll
    for (int i = 0; i < 8; ++i) r[i] = (bf16_t)((float)a[i] + (float)b[i]);
    return r;
}

// convert 8 fp32 -> 8 bf16 (16B store)
static __device__ inline void cvt8(const float* src, bf16_t* dst, size_t idx) {
    float4 a = *(const float4*)(src + idx);
    float4 c = *(const float4*)(src + idx + 4);
    uint4 u;
    u.x = pack_bf2(a.x, a.y);
    u.y = pack_bf2(a.z, a.w);
    u.z = pack_bf2(c.x, c.y);
    u.w = pack_bf2(c.z, c.w);
    *(uint4*)(dst + idx) = u;
}

// ---------------------------------------------------------------------------
// 64x64-tile GEMM body (sgconv_half-proven occupancy recipe applied to small
// GEMMs): C = (A[M,K]*B[N,K]^T (+bias_col)(+bias_row)) * cscale.
// BK=32, 4 waves (2x2 of 32x32), 8KB LDS -> high blocks/CU. Chunk-XOR
// swizzle ((row>>1)&3) on BOTH gload source and ds_read (linear LDS dest).
// r16 lesson: 128^2 tiles at 1.5 blocks/CU are latency-starved; this body
// at >=4 blocks/CU is the measured-good regime (r11).
// ---------------------------------------------------------------------------
template <typename TC>
__device__ inline void gemm_body64(
    const bf16_t* __restrict__ A, int lda,
    const bf16_t* __restrict__ B, int ldb,
    const float* __restrict__ bias_col, const float* __restrict__ bias_row,
    float cscale,
    TC* __restrict__ C, int ldc, int K, int m0, int n0)
{
    __shared__ bf16_t As[64 * 32];
    __shared__ bf16_t Bs[64 * 32];

    const int tid = threadIdx.x;
    const int lane = tid & 63, wave = tid >> 6;
    const int wm = wave & 1, wn = wave >> 1;
    const int lo16 = lane & 15, quad = lane >> 4;

    // staging: thread covers (row = tid/4, 16B chunk slot = tid%4), src XOR'd
    const int r0 = tid >> 2, s0 = tid & 3;
    const int c0 = s0 ^ ((r0 >> 1) & 3);
    const bf16_t* ga = A + (size_t)(m0 + r0) * lda + c0 * 8;
    const bf16_t* gb = B + (size_t)(n0 + r0) * ldb + c0 * 8;
    const bf16_t* la = As + wave * 512;   // wave-uniform LDS bases (lane*16B)
    const bf16_t* lb = Bs + wave * 512;

    int aoff[2], boff[2];
#pragma unroll
    for (int t = 0; t < 2; ++t) {
        const int ra = wm * 32 + t * 16 + lo16;
        aoff[t] = ra * 32 + ((quad ^ ((ra >> 1) & 3)) << 3);
        const int rb = wn * 32 + t * 16 + lo16;
        boff[t] = rb * 32 + ((quad ^ ((rb >> 1) & 3)) << 3);
    }

    floatx4 acc[2][2] = {};

    for (int k0 = 0; k0 < K; k0 += 32) {
        __syncthreads();
        gload_lds16(ga + k0, la);
        gload_lds16(gb + k0, lb);
        __syncthreads();

        bf16x8 af[2], bfv[2];
#pragma unroll
        for (int t = 0; t < 2; ++t) {
            af[t]  = *(const bf16x8*)(As + aoff[t]);
            bfv[t] = *(const bf16x8*)(Bs + boff[t]);
        }
#pragma unroll
        for (int mt = 0; mt < 2; ++mt)
#pragma unroll
            for (int nt = 0; nt < 2; ++nt)
                acc[mt][nt] = __builtin_amdgcn_mfma_f32_16x16x32_bf16(
                    af[mt], bfv[nt], acc[mt][nt], 0, 0, 0);
    }

#pragma unroll
    for (int nt = 0; nt < 2; ++nt) {
        const int gn = n0 + wn * 32 + nt * 16 + lo16;
        const float bc = bias_col ? bias_col[gn] : 0.f;
#pragma unroll
        for (int mt = 0; mt < 2; ++mt) {
#pragma unroll
            for (int r = 0; r < 4; ++r) {
                const int gm = m0 + wm * 32 + mt * 16 + quad * 4 + r;
                float v = acc[mt][nt][r] + bc;
                if (bias_row) v += bias_row[gm];
                store_c(C, (size_t)gm * ldc + gn, v * cscale);
            }
        }
    }
}

// Bulk fp32->bf16: q/k/v inputs, 4 weight matrices, AND the sg matrix.
// All streaming blocks share one low-VGPR, no-LDS kernel -> high occupancy.
// grid 2944: 896 input/weight blocks + 2048 sg blocks, 8192 elems each.
__global__ __launch_bounds__(256) void prep(
    const float* __restrict__ query, const float* __restrict__ key, const float* __restrict__ value,
    const float* __restrict__ Wq, const float* __restrict__ Wk,
    const float* __restrict__ Wv, const float* __restrict__ Wo,
    const float* __restrict__ sg,
    bf16_t* qB, bf16_t* kB, bf16_t* vB,
    bf16_t* wqB, bf16_t* wkB, bf16_t* wvB, bf16_t* woB,
    bf16_t* sgb)
{
    const int b = blockIdx.x;
    const float* src; bf16_t* dst; size_t base;
    if      (b < 256) { src = query; dst = qB;  base = (size_t)b * 8192; }
    else if (b < 512) { src = key;   dst = kB;  base = (size_t)(b - 256) * 8192; }
    else if (b < 768) { src = value; dst = vB;  base = (size_t)(b - 512) * 8192; }
    else if (b < 800) { src = Wq;    dst = wqB; base = (size_t)(b - 768) * 8192; }
    else if (b < 832) { src = Wk;    dst = wkB; base = (size_t)(b - 800) * 8192; }
    else if (b < 864) { src = Wv;    dst = wvB; base = (size_t)(b - 832) * 8192; }
    else if (b < 896) { src = Wo;    dst = woB; base = (size_t)(b - 864) * 8192; }
    else              { src = sg;    dst = sgb; base = (size_t)(b - 896) * 8192; }
#pragma unroll
    for (int it = 0; it < 4; ++it)
        cvt8(src, dst, base + (size_t)it * 2048 + threadIdx.x * 8);
}

// QKV projections: 3 GEMMs x 512 blocks of 64x64 tiles = 1536 blocks = 6/CU
// (r16 lesson: the 384-block 128^2 version was grid-starved at 1.5/CU).
// Q output is pre-scaled by (1/sqrt(D))*log2(e) so flash can use a bare exp2.
__global__ __launch_bounds__(256) void proj_qkv(
    const bf16_t* __restrict__ qB, const bf16_t* __restrict__ wqB, const float* __restrict__ bq,
    const bf16_t* __restrict__ kB, const bf16_t* __restrict__ wkB, const float* __restrict__ bk,
    const bf16_t* __restrict__ wvB, const bf16_t* __restrict__ vB, const float* __restrict__ bv,
    bf16_t* __restrict__ q, bf16_t* __restrict__ k, bf16_t* __restrict__ vt, float qscale)
{
    const int b = blockIdx.x;
    if (b < 1024) {                       // Q and K: M=4096 (64 tiles), N=512 (8 tiles)
        const int i = b & 511;
        const int m0 = (i & 63) * 64, n0 = (i >> 6) * 64;
        if (b < 512)
            gemm_body64<bf16_t>(qB, 512, wqB, 512, bq, nullptr, qscale, q, 512, 512, m0, n0);
        else
            gemm_body64<bf16_t>(kB, 512, wkB, 512, bk, nullptr, 1.f, k, 512, 512, m0, n0);
    } else {                              // V^T: M=512 (8 tiles), N=4096 (64 tiles)
        const int i = b - 1024;
        const int m0 = (i & 7) * 64, n0 = (i >> 3) * 64;
        gemm_body64<bf16_t>(wvB, 512, vB, 512, nullptr, bv, 1.f, vt, 4096, 512, m0, n0);
    }
}

// ---------------------------------------------------------------------------
// sgconv, 2-way K-split (r11 measured-best): o2p[kb] = partial over K-half kb.
// 64x64 tiles, K=2048/block -> grid 1024 = 4 blocks/CU. bf16 partials (8MB);
// out_proj sums the two halves during A-staging.
// ---------------------------------------------------------------------------
__global__ __launch_bounds__(256) void sgconv_half(
    const bf16_t* __restrict__ sgb, const bf16_t* __restrict__ aot,
    bf16_t* __restrict__ o2p)
{
    const int bid = blockIdx.x;
    const int i = bid & 511;
    const int kb = bid >> 9;          // 0 or 1
    const int m0 = (i & 63) * 64;     // token rows
    const int n0 = (i >> 6) * 64;     // dim cols
    const int kbase = kb * 2048;

    __shared__ bf16_t As[64 * 64];
    __shared__ bf16_t Bs[64 * 64];

    const int tid = threadIdx.x;
    const int lane = tid & 63, wave = tid >> 6;
    const int wm = wave & 1, wn = wave >> 1;
    const int lo16 = lane & 15, quad = lane >> 4;

    // staging: issue j covers rows j*32 + tid/8; chunk slot tid&7, src chunk XOR'd
    const int r0 = tid >> 3, s0 = tid & 7;
    const int c0 = s0 ^ (r0 & 7);          // rows +32 keep the same (row&7)
    const bf16_t* gaA = sgb + (size_t)(m0 + r0) * 4096 + kbase + c0 * 8;
    const bf16_t* gaB = aot + (size_t)(n0 + r0) * 4096 + kbase + c0 * 8;
    const bf16_t* laA0 = As + wave * 512;           // 8 rows x 64 per wave
    const bf16_t* laA1 = As + 2048 + wave * 512;
    const bf16_t* laB0 = Bs + wave * 512;
    const bf16_t* laB1 = Bs + 2048 + wave * 512;

    // swizzled fragment read offsets (elems)
    int aoff[2][2], boff[2][2];
#pragma unroll
    for (int t = 0; t < 2; ++t)
#pragma unroll
        for (int kk = 0; kk < 2; ++kk) {
            const int ra = wm * 32 + t * 16 + lo16;
            aoff[t][kk] = ra * 64 + (((kk * 4 + quad) ^ (ra & 7)) << 3);
            const int rb = wn * 32 + t * 16 + lo16;
            boff[t][kk] = rb * 64 + (((kk * 4 + quad) ^ (rb & 7)) << 3);
        }

    floatx4 acc[2][2] = {};

    for (int k0 = 0; k0 < 2048; k0 += 64) {
        __syncthreads();
        gload_lds16(gaA + k0, laA0);
        gload_lds16(gaA + (size_t)32 * 4096 + k0, laA1);
        gload_lds16(gaB + k0, laB0);
        gload_lds16(gaB + (size_t)32 * 4096 + k0, laB1);
        __syncthreads();

        bf16x8 af[2][2], bfv[2][2];
#pragma unroll
        for (int t = 0; t < 2; ++t)
#pragma unroll
            for (int kk = 0; kk < 2; ++kk) {
                af[t][kk]  = *(const bf16x8*)(As + aoff[t][kk]);
                bfv[t][kk] = *(const bf16x8*)(Bs + boff[t][kk]);
            }
#pragma unroll
        for (int mt = 0; mt < 2; ++mt)
#pragma unroll
            for (int nt = 0; nt < 2; ++nt)
#pragma unroll
                for (int kk = 0; kk < 2; ++kk)
                    acc[mt][nt] = __builtin_amdgcn_mfma_f32_16x16x32_bf16(
                        af[mt][kk], bfv[nt][kk], acc[mt][nt], 0, 0, 0);
    }

    bf16_t* dst = o2p + (size_t)kb * ((size_t)4096 * 512);
#pragma unroll
    for (int nt = 0; nt < 2; ++nt) {
        const int gn = n0 + wn * 32 + nt * 16 + lo16;
#pragma unroll
        for (int mt = 0; mt < 2; ++mt)
#pragma unroll
            for (int r = 0; r < 4; ++r) {
                const int gm = m0 + wm * 32 + mt * 16 + quad * 4 + r;
                dst[(size_t)gm * 512 + gn] = (bf16_t)acc[mt][nt][r];
            }
    }
}

// out = (o2a+o2b) @ Wo^T + bo. TM=TN=64 (wave tile 32x32) -> grid 512 = 2/CU.
// The two sgconv K-half partials are summed during A-staging.
__global__ __launch_bounds__(256) void out_proj(
    const bf16_t* __restrict__ o2a, const bf16_t* __restrict__ o2b,
    const bf16_t* __restrict__ woB,
    const float* __restrict__ bo, float* __restrict__ out)
{
    const int i = blockIdx.x, x = i & 7, t = i >> 3;
    const int n0 = (t & 7) * 64;
    const int m0 = ((t >> 3) * 8 + x) * 64;

    __shared__ bf16_t As[64 * 68];
    __shared__ bf16_t Bs[64 * 68];

    const int tid = threadIdx.x;
    const int lane = tid & 63, wave = tid >> 6;
    const int wm = wave & 1, wn = wave >> 1;
    const int lo16 = lane & 15, quad = lane >> 4;
    const int sr = tid >> 2, sc = (tid & 3) * 8;

    floatx4 acc[2][2] = {};

    for (int k0 = 0; k0 < 512; k0 += 32) {
        const size_t aidx = (size_t)(m0 + sr) * 512 + k0 + sc;
        bf16x8 a0 = add8(*(const bf16x8*)(o2a + aidx), *(const bf16x8*)(o2b + aidx));
        bf16x8 b0 = *(const bf16x8*)(woB + (size_t)(n0 + sr) * 512 + k0 + sc);
        __syncthreads();
        *(bf16x8*)(&As[sr * 68 + sc]) = a0;
        *(bf16x8*)(&Bs[sr * 68 + sc]) = b0;
        __syncthreads();

        bf16x8 af[2], bfv[2];
#pragma unroll
        for (int mt = 0; mt < 2; ++mt)
            af[mt] = *(const bf16x8*)(&As[(wm * 32 + mt * 16 + lo16) * 68 + quad * 8]);
#pragma unroll
        for (int nt = 0; nt < 2; ++nt)
            bfv[nt] = *(const bf16x8*)(&Bs[(wn * 32 + nt * 16 + lo16) * 68 + quad * 8]);
#pragma unroll
        for (int mt = 0; mt < 2; ++mt)
#pragma unroll
            for (int nt = 0; nt < 2; ++nt)
                acc[mt][nt] = __builtin_amdgcn_mfma_f32_16x16x32_bf16(
                    af[mt], bfv[nt], acc[mt][nt], 0, 0, 0);
    }

#pragma unroll
    for (int nt = 0; nt < 2; ++nt) {
        const int gn = n0 + wn * 32 + nt * 16 + lo16;
        const float bc = bo[gn];
#pragma unroll
        for (int mt = 0; mt < 2; ++mt)
#pragma unroll
            for (int r = 0; r < 4; ++r) {
                const int gm = m0 + wm * 32 + mt * 16 + quad * 4 + r;
                out[(size_t)gm * 512 + gn] = acc[mt][nt][r] + bc;
            }
    }
}

// ---------------------------------------------------------------------------
// Flash attention. Pure 1024-block grid (4 blocks/CU).
// Q comes in pre-scaled by (1/sqrt(D))*log2(e) -> bare v_exp_f32.
// Softmax denominator accumulated via ones-operand MFMA.
// (setprio removed: r4 measured 52.6->53.5 regression; r10/r11 confirm 52.9.)
// ---------------------------------------------------------------------------
__global__ __launch_bounds__(256, 4) void flash_attn(
    const bf16_t* __restrict__ q, const bf16_t* __restrict__ kk,
    const bf16_t* __restrict__ vt, float* __restrict__ op,
    float* __restrict__ lp)
{
    const int fid = blockIdx.x;

    const int N = 4096, D = 512;
    const int h   = fid & 7;
    const int qb  = (fid >> 3) & 31;
    const int qtr = fid >> 8;
    const int t0  = qtr * 1024;

    const int tid = threadIdx.x;
    const int w = tid >> 6, lane = tid & 63;
    const int lo16 = lane & 15, quad = lane >> 4;

    __shared__ bf16_t Ks[64 * 72];
    __shared__ bf16_t Vs[64 * 72];
    __shared__ bf16_t Ps[4][32 * 72];

    const bf16_t* qp = q + (size_t)(qb * 128 + w * 32 + lo16) * D + h * 64 + quad * 8;
    bf16x8 qf[2][2];
    qf[0][0] = *(const bf16x8*)qp;
    qf[0][1] = *(const bf16x8*)(qp + 32);
    qf[1][0] = *(const bf16x8*)(qp + 16 * D);
    qf[1][1] = *(const bf16x8*)(qp + 16 * D + 32);

    const int srow = tid >> 2, sc = (tid & 3) * 16;
    const bf16_t* ksrc = kk + (size_t)(t0 + srow) * D + h * 64 + sc;
    const bf16_t* vsrc = vt + (size_t)(h * 64 + srow) * N + t0 + sc;
    bf16_t* kdst = &Ks[srow * 72 + sc];
    bf16_t* vdst = &Vs[srow * 72 + sc];

    bf16x8 ones;
#pragma unroll
    for (int i = 0; i < 8; ++i) ones[i] = (bf16_t)1.0f;

    floatx4 o[4][2] = {};
    floatx4 lacc[2] = {};

    bf16x8 kr0 = *(const bf16x8*)ksrc;
    bf16x8 kr1 = *(const bf16x8*)(ksrc + 8);
    bf16x8 vr0 = *(const bf16x8*)vsrc;
    bf16x8 vr1 = *(const bf16x8*)(vsrc + 8);

    for (int it = 0; it < 16; ++it) {
        __syncthreads();
        *(bf16x8*)kdst = kr0;  *(bf16x8*)(kdst + 8) = kr1;
        *(bf16x8*)vdst = vr0;  *(bf16x8*)(vdst + 8) = vr1;
        __syncthreads();
        if (it < 15) {
            const bf16_t* kn = ksrc + (size_t)(it + 1) * 64 * D;
            const bf16_t* vn = vsrc + (it + 1) * 64;
            kr0 = *(const bf16x8*)kn;  kr1 = *(const bf16x8*)(kn + 8);
            vr0 = *(const bf16x8*)vn;  vr1 = *(const bf16x8*)(vn + 8);
        }

        // S^T = K·Q^T : D[m=tok][n=q]
        floatx4 s[4][2];
#pragma unroll
        for (int tt = 0; tt < 4; ++tt) {
            bf16x8 kf0 = *(const bf16x8*)(&Ks[(tt * 16 + lo16) * 72 + quad * 8]);
            bf16x8 kf1 = *(const bf16x8*)(&Ks[(tt * 16 + lo16) * 72 + 32 + quad * 8]);
#pragma unroll
            for (int qt = 0; qt < 2; ++qt) {
                floatx4 a = {};
                a = __builtin_amdgcn_mfma_f32_16x16x32_bf16(kf0, qf[qt][0], a, 0, 0, 0);
                a = __builtin_amdgcn_mfma_f32_16x16x32_bf16(kf1, qf[qt][1], a, 0, 0, 0);
                s[tt][qt] = a;
            }
        }
        // exp2 + packed b64 P writes (row sums come from the ones-MFMA below)
#pragma unroll
        for (int tt = 0; tt < 4; ++tt)
#pragma unroll
            for (int qt = 0; qt < 2; ++qt) {
                float e0 = __builtin_amdgcn_exp2f(s[tt][qt][0]);
                float e1 = __builtin_amdgcn_exp2f(s[tt][qt][1]);
                float e2 = __builtin_amdgcn_exp2f(s[tt][qt][2]);
                float e3 = __builtin_amdgcn_exp2f(s[tt][qt][3]);
                uint2 pk;
                pk.x = pack_bf2(e0, e1);
                pk.y = pack_bf2(e2, e3);
                *(uint2*)(&Ps[w][(qt * 16 + lo16) * 72 + tt * 16 + quad * 4]) = pk;
            }
        // PV: o[dim][q] += V·P^T ; l[q] += 1·P^T (denominator via MFMA)
#pragma unroll
        for (int ks = 0; ks < 2; ++ks) {
            bf16x8 pf0 = *(const bf16x8*)(&Ps[w][lo16 * 72 + ks * 32 + quad * 8]);
            bf16x8 pf1 = *(const bf16x8*)(&Ps[w][(16 + lo16) * 72 + ks * 32 + quad * 8]);
            lacc[0] = __builtin_amdgcn_mfma_f32_16x16x32_bf16(ones, pf0, lacc[0], 0, 0, 0);
            lacc[1] = __builtin_amdgcn_mfma_f32_16x16x32_bf16(ones, pf1, lacc[1], 0, 0, 0);
#pragma unroll
            for (int t = 0; t < 4; ++t) {
                bf16x8 vf = *(const bf16x8*)(&Vs[(t * 16 + lo16) * 72 + ks * 32 + quad * 8]);
                o[t][0] = __builtin_amdgcn_mfma_f32_16x16x32_bf16(vf, pf0, o[t][0], 0, 0, 0);
                o[t][1] = __builtin_amdgcn_mfma_f32_16x16x32_bf16(vf, pf1, o[t][1], 0, 0, 0);
            }
        }
    }

    const int g = fid & 255;
    float* opw = op + ((size_t)qtr * 256 + g) * 8192;
#pragma unroll
    for (int t = 0; t < 4; ++t)
#pragma unroll
        for (int pt = 0; pt < 2; ++pt)
#pragma unroll
            for (int r = 0; r < 4; ++r)
                opw[(t * 16 + quad * 4 + r) * 128 + w * 32 + pt * 16 + lo16] = o[t][pt][r];

    if (quad == 0) {   // all 4 lacc rows identical (ones A-operand); take r=0
        float* lpw = lp + ((size_t)qtr * 256 + g) * 128;
        lpw[w * 32 + lo16] = lacc[0][0];
        lpw[w * 32 + 16 + lo16] = lacc[1][0];
    }
}

// grid 1024 (4/CU): bid = (g, quarter). Each block does 2048 of the 8192 elems.
__global__ __launch_bounds__(256) void attn_combine(
    const float* __restrict__ op, const float* __restrict__ lp, bf16_t* __restrict__ aot)
{
    const int bid = blockIdx.x;
    const int g = bid >> 2, qu = bid & 3;
    const int h = g & 7, qb = g >> 3;
    const int tid = threadIdx.x;
    __shared__ float ls[128];
    if (tid < 128) {
        float s = 0.f;
#pragma unroll
        for (int qtr = 0; qtr < 4; ++qtr)
            s += lp[((size_t)qtr * 256 + g) * 128 + tid];
        ls[tid] = 1.0f / s;
    }
    __syncthreads();
    const float* b0 = op + (size_t)g * 8192;
    const size_t QS = (size_t)256 * 8192;
#pragma unroll
    for (int i = 0; i < 8; ++i) {
        int idx = qu * 2048 + i * 256 + tid;
        float v = b0[idx] + b0[QS + idx] + b0[2 * QS + idx] + b0[3 * QS + idx];
        int dim = idx >> 7, qc = idx & 127;
        aot[(size_t)(h * 64 + dim) * 4096 + qb * 128 + qc] = (bf16_t)(v * ls[qc]);
    }
}

extern "C" void kernel_launch(void* const* d_in, const int* in_sizes, int n_in,
                              void* d_out, int out_size, void* d_ws, size_t ws_size,
                              hipStream_t stream)
{
    const int N = 4096, D = 512;
    const float* query = (const float*)d_in[0];
    const float* key_t = (const float*)d_in[1];
    const float* value = (const float*)d_in[2];
    const float* Wq = (const float*)d_in[3];
    const float* bq = (const float*)d_in[4];
    const float* Wk = (const float*)d_in[5];
    const float* bk = (const float*)d_in[6];
    const float* Wv = (const float*)d_in[7];
    const float* bv = (const float*)d_in[8];
    const float* Wo = (const float*)d_in[9];
    const float* bo = (const float*)d_in[10];
    const float* sg = (const float*)d_in[11];
    float* out = (float*)d_out;

    const size_t ND = (size_t)N * D;
    const size_t DD = (size_t)D * D;

    char* base = (char*)d_ws;
    bf16_t* q    = (bf16_t*)base;
    bf16_t* kk   = q   + ND;
    bf16_t* vt   = kk  + ND;
    bf16_t* aot  = vt  + ND;
    bf16_t* sgb  = aot + ND;
    char* regA   = (char*)(sgb + (size_t)N * N);
    // region A, phase 1: prep inputs (13.5MB)
    bf16_t* qB   = (bf16_t*)regA;
    bf16_t* kB   = qB + ND;
    bf16_t* vB   = kB + ND;
    bf16_t* wqB  = vB + ND;
    bf16_t* wkB  = wqB + DD;
    bf16_t* wvB  = wkB + DD;
    // region A, phase 2: flash partials op (32MB)
    float* op    = (float*)regA;
    char* tail   = regA + (size_t)4 * 256 * 8192 * 4;   // 32MB
    float*  lp   = (float*)tail;
    bf16_t* woB  = (bf16_t*)(lp + (size_t)4 * 256 * 128);
    bf16_t* o2   = woB + DD;           // two bf16 partials: 2 x 4MB
    bf16_t* o2b  = o2 + ND;

    const dim3 blk(256);

    prep<<<2944, blk, 0, stream>>>(query, key_t, value, Wq, Wk, Wv, Wo, sg,
                                   qB, kB, vB, wqB, wkB, wvB, woB, sgb);

    const float qscale = 1.44269504088896f / sqrtf((float)D);
    proj_qkv<<<1536, blk, 0, stream>>>(qB, wqB, bq, kB, wkB, bk,
                                       wvB, vB, bv, q, kk, vt, qscale);

    flash_attn<<<1024, blk, 0, stream>>>(q, kk, vt, op, lp);
    attn_combine<<<1024, blk, 0, stream>>>(op, lp, aot);

    sgconv_half<<<1024, blk, 0, stream>>>(sgb, aot, o2);
    out_proj<<<512, blk, 0, stream>>>(o2, o2b, woB, bo, out);

    (void)in_sizes; (void)n_in; (void)out_size; (void)ws_size;
}